// Round 3
// baseline (2174.846 us; speedup 1.0000x reference)
//
#include <hip/hip_runtime.h>
#include <stdint.h>

typedef unsigned short u16;
typedef unsigned int u32;
typedef __attribute__((ext_vector_type(4))) float f32x4;
typedef __attribute__((ext_vector_type(8))) short bf16x8;

#define MROWS 16384
#define NP    2560   // padded N / K for 2500-dims
#define K1P   2688   // padded K for 2675 (train_feat / W1_self)

// ---------------- helpers ----------------

__device__ __forceinline__ u16 f2bf(float f) {
    u32 u = __float_as_uint(f);
    u32 r = (u + 0x7fffu + ((u >> 16) & 1u)) >> 16;   // round-to-nearest-even
    return (u16)r;
}

__device__ __forceinline__ void async_ld16(const void* g, void* l) {
    __builtin_amdgcn_global_load_lds((const __attribute__((address_space(1))) u32*)g,
                                     (__attribute__((address_space(3))) u32*)l,
                                     16, 0, 0);
}

__device__ __forceinline__ u32 lds_b(const void* p) {
    return (u32)(uintptr_t)(const __attribute__((address_space(3))) void*)p;
}

// ---------------- prep kernels ----------------

__global__ void cvt_pad(const float* __restrict__ src, u16* __restrict__ dst,
                        int R, int C, int Cp) {
    const int r = blockIdx.x;
    u16* drow = dst + (size_t)r * Cp;
    if (r < R) {
        const float* srow = src + (size_t)r * C;
        for (int c = threadIdx.x; c < Cp; c += blockDim.x)
            drow[c] = (c < C) ? f2bf(srow[c]) : (u16)0;
    } else {
        for (int c = threadIdx.x; c < Cp; c += blockDim.x) drow[c] = 0;
    }
}

__global__ void pad_vec(const float* __restrict__ src, float* __restrict__ dst,
                        int n, int np) {
    int i = blockIdx.x * blockDim.x + threadIdx.x;
    if (i < np) dst[i] = (i < n) ? src[i] : 0.f;
}

// gene_feat [2500,2500] fp32 -> dst [NP,NP] bf16, dst[n][k] = src[k][n], padded 0
__global__ void transpose_cvt(const float* __restrict__ src, u16* __restrict__ dst) {
    __shared__ float t[64][65];
    const int n0 = blockIdx.x * 64;
    const int k0 = blockIdx.y * 64;
    const int tx = threadIdx.x, ty = threadIdx.y;  // (64,4)
    for (int i = ty; i < 64; i += 4) {
        int k = k0 + i, n = n0 + tx;
        t[i][tx] = (k < 2500 && n < 2500) ? src[(size_t)k * 2500 + n] : 0.f;
    }
    __syncthreads();
    for (int i = ty; i < 64; i += 4)
        dst[(size_t)(n0 + i) * NP + k0 + tx] = f2bf(t[tx][i]);
}

__global__ void build_counts(const int* __restrict__ esrc, const int* __restrict__ edst,
                             int E, float* __restrict__ acnt) {
    int i = blockIdx.x * blockDim.x + threadIdx.x;
    if (i < E) atomicAdd(&acnt[(size_t)edst[i] * NP + esrc[i]], 1.0f);
}

__global__ void row_rdeg(const float* __restrict__ acnt, float* __restrict__ rdeg) {
    const int row = blockIdx.x;
    const float4* p = (const float4*)(acnt + (size_t)row * NP);
    float s = 0.f;
    for (int i = threadIdx.x; i < NP / 4; i += 64) {
        float4 v = p[i];
        s += v.x + v.y + v.z + v.w;
    }
    #pragma unroll
    for (int off = 32; off > 0; off >>= 1) s += __shfl_down(s, off, 64);
    if (threadIdx.x == 0) rdeg[row] = 1.f / fmaxf(s, 1.f);
}

// ---------------- main MFMA GEMM: 256x256, 8-phase, full one-phase-ahead reads --------
// C[M,N](bf16) = epilogue( A1[M,K1] @ B1[N,K1]^T (+ A2[M,K2] @ B2[N,K2]^T) )
// 512 threads = 8 waves (2M x 4N), per-wave 128x64, BK=64.
// LDS: 2 buffers x (A 256x64 + B 256x64) bf16 = 128 KiB, chunk-XOR swizzled.
//
// EVERY ds_read is issued one full phase before its lgkm-wait, so its drain hides
// under the previous phase's MFMA cluster. Per K-tile (4 phases):
//   P1: Q00(a1*b01X)  wait(4)  issue b23        P2: Q01(a1*b23)  wait(8)  issue a2
//   P3: Q11(a2*b23)   wait(4)  issue b01Y(next) P4: Q10(a2*b01X) no-wait  issue a1(next)
// b01 is double-banked (X/Y alternate per K-tile); a1/a2/b23 single-banked (WAR gap >= 2
// phases, enforced by register deps). Stages shift earlier to match; vmcnt(4) at every
// even phase drains exactly the 2 stage-halves the next phase's read-issue needs.
// Ledger (steady, loads): P2 drains buf1.B | P4 buf1.A | P6 buf0.B' | P8 buf0.A'.

#define DSR(dst, ad, off) \
    asm volatile("ds_read_b128 %0, %1 offset:%2" : "=v"(dst) : "v"(ad), "i"(off))

#define RD_A(SET, BUF, QM) do { \
    DSR(SET[0][0], adA0, (BUF)*32768 + (QM)*8192 + 0);    \
    DSR(SET[0][1], adA1, (BUF)*32768 + (QM)*8192 + 0);    \
    DSR(SET[1][0], adA0, (BUF)*32768 + (QM)*8192 + 2048); \
    DSR(SET[1][1], adA1, (BUF)*32768 + (QM)*8192 + 2048); \
    DSR(SET[2][0], adA0, (BUF)*32768 + (QM)*8192 + 4096); \
    DSR(SET[2][1], adA1, (BUF)*32768 + (QM)*8192 + 4096); \
    DSR(SET[3][0], adA0, (BUF)*32768 + (QM)*8192 + 6144); \
    DSR(SET[3][1], adA1, (BUF)*32768 + (QM)*8192 + 6144); \
} while (0)

// B frag pair: BASE=0 -> ni{0,1} (b01), BASE=4096 -> ni{2,3} (b23)
#define RD_BP(SET, BUF, BASE) do { \
    DSR(SET[0][0], adB0, (BUF)*32768 + (BASE));        \
    DSR(SET[0][1], adB1, (BUF)*32768 + (BASE));        \
    DSR(SET[1][0], adB0, (BUF)*32768 + (BASE) + 2048); \
    DSR(SET[1][1], adB1, (BUF)*32768 + (BASE) + 2048); \
} while (0)

// counted lgkm wait + scheduler fence (rule #18: MFMA must not hoist above the wait)
#define WAITLG(N) do { \
    asm volatile("s_waitcnt lgkmcnt(" #N ")" ::: "memory"); \
    __builtin_amdgcn_sched_barrier(0); \
} while (0)

#define MFMA_Q(QM, QN, ASET, BSET) do { \
    __builtin_amdgcn_s_setprio(1); \
    _Pragma("unroll") \
    for (int mi_ = 0; mi_ < 4; ++mi_) { \
        _Pragma("unroll") \
        for (int ni_ = 0; ni_ < 2; ++ni_) { \
            f32x4 c_ = acc[(QM)*4 + mi_][(QN)*2 + ni_]; \
            c_ = __builtin_amdgcn_mfma_f32_16x16x32_bf16(ASET[mi_][0], BSET[ni_][0], c_, 0, 0, 0); \
            c_ = __builtin_amdgcn_mfma_f32_16x16x32_bf16(ASET[mi_][1], BSET[ni_][1], c_, 0, 0, 0); \
            acc[(QM)*4 + mi_][(QN)*2 + ni_] = c_; \
        } \
    } \
    __builtin_amdgcn_s_setprio(0); \
} while (0)

#define XFEN() asm volatile("" ::: "memory")
#define XBAR() do { XFEN(); __builtin_amdgcn_s_barrier(); XFEN(); } while (0)
#define WVM4() asm volatile("s_waitcnt vmcnt(4)" ::: "memory")

template<bool PAIR2, bool BIAS_RELU>
__global__ __launch_bounds__(512, 2) void gemm256(
    const u16* __restrict__ A1, const u16* __restrict__ B1, int K1,
    const u16* __restrict__ A2, const u16* __restrict__ B2, int K2,
    const float* __restrict__ epi, u16* __restrict__ C, int N)
{
    __shared__ __align__(16) u16 lA[2 * 256 * 64];
    __shared__ __align__(16) u16 lB[2 * 256 * 64];

    const int tid  = threadIdx.x;
    // bijective XCD swizzle (gridDim.x = 640, 640 % 8 == 0)
    const int nwg  = gridDim.x;
    const int orig = blockIdx.x;
    const int swz  = (orig & 7) * (nwg >> 3) + (orig >> 3);
    const int nt   = N >> 8;                 // 10 col-tiles
    const int bm   = (swz / nt) << 8;
    const int bn   = (swz % nt) << 8;

    const int wave = tid >> 6, lane = tid & 63;
    const int wr   = (wave >> 2) << 7;       // 0 or 128
    const int wc   = (wave & 3) << 6;        // 0,64,128,192
    const int lrow = lane & 15, lkq = (lane >> 4) & 3;
    const int o0   = ((lkq ^ (lrow & 7)) << 3);   // elem offset, ks=0 chunk

    // ds_read base addresses (bytes); ks=1 chunk = ks=0 chunk ^ 32 elems = ^64 B
    const u32 adA0 = lds_b(lA + (wr + lrow) * 64 + o0);
    const u32 adA1 = adA0 ^ 64;
    const u32 adB0 = lds_b(lB + (wc + lrow) * 64 + o0);
    const u32 adB1 = adB0 ^ 64;

    // staging constants: thread t -> row t>>3, physical chunk t&7 (lane-linear LDS dest)
    const int sr   = tid >> 3;
    const int pc   = tid & 7;
    const int swzc = ((pc ^ (sr & 7)) << 3); // source logical chunk offset (elems)
    u16* const dA  = lA + sr * 64 + pc * 8;
    u16* const dB  = lB + sr * 64 + pc * 8;

    const int nk1 = K1 >> 6;
    const int nkt = nk1 + (PAIR2 ? (K2 >> 6) : 0);

    f32x4 acc[8][4] = {};
    bf16x8 a1[4][2], a2[4][2], b23[2][2], b01A[2][2], b01B[2][2];

    // stage one 128-row half-tile (2 x global_load_lds / thread) of A(mat=0)/B(mat=1)
    auto STAGE = [&](int mat, int buf, int half, int kt) {
        int v = (kt < nkt) ? kt : kt - nkt;  // tail: clamp to valid tile (lands in dead region)
        const u16* base; int K, ko;
        if (!PAIR2 || v < nk1) { base = mat ? B1 : A1; K = K1; ko = v << 6; }
        else                   { base = mat ? B2 : A2; K = K2; ko = (v - nk1) << 6; }
        const int rb = (mat ? bn : bm) + (half << 7) + sr;
        u16* d = (mat ? dB : dA) + buf * 16384 + half * 8192;
        const u16* g = base + (size_t)rb * K + ko + swzc;
        async_ld16(g, d);
        async_ld16(g + (size_t)64 * K, d + 4096);
    };

    // prologue: buf0 full (tile0) + buf1.B (tile1); drain buf0, leave buf1.B in flight
    STAGE(1, 0, 0, 0); STAGE(1, 0, 1, 0);    // buf0.B
    STAGE(0, 0, 0, 0); STAGE(0, 0, 1, 0);    // buf0.A
    STAGE(1, 1, 0, 1); STAGE(1, 1, 1, 1);    // buf1.B
    WVM4();                                   // 12 -> 4: buf0 landed, buf1.B in flight
    XBAR();
    RD_BP(b01A, 0, 0);                        // issues for P1 (12 ds in flight: b01A+a1)
    RD_A(a1, 0, 0);

    const int niter = nkt >> 1;               // nkt always even here
    #pragma unroll 1
    for (int i = 0; i < niter; ++i) {
        const int t1 = 2 * i + 1, t2 = 2 * i + 2, t3 = 2 * i + 3;
        // P1: Q00(e) <- a1,b01A.  issue b23(buf0)
        STAGE(0, 1, 0, t1);
        XBAR(); RD_BP(b23, 0, 4096); WAITLG(4); MFMA_Q(0, 0, a1, b01A); XBAR();
        // P2: Q01(e) <- a1,b23.   issue a2(buf0); WVM drains buf1.B for P3
        STAGE(0, 1, 1, t1); WVM4();
        XBAR(); RD_A(a2, 0, 1); WAITLG(8); MFMA_Q(0, 1, a1, b23); XBAR();
        // P3: Q11(e) <- a2,b23.   issue b01B(buf1)
        STAGE(1, 0, 0, t2);
        XBAR(); RD_BP(b01B, 1, 0); WAITLG(4); MFMA_Q(1, 1, a2, b23); XBAR();
        // P4: Q10(e) <- a2,b01A.  issue a1(buf1); WVM drains buf1.A; no lgkm wait
        STAGE(1, 0, 1, t2); WVM4();
        XBAR(); RD_A(a1, 1, 0); MFMA_Q(1, 0, a2, b01A); XBAR();
        // P5: Q00(o) <- a1,b01B.  issue b23(buf1)
        STAGE(0, 0, 0, t2);
        XBAR(); RD_BP(b23, 1, 4096); WAITLG(4); MFMA_Q(0, 0, a1, b01B); XBAR();
        // P6: Q01(o) <- a1,b23.   issue a2(buf1); WVM drains buf0.B(e2) for P7
        STAGE(0, 0, 1, t2); WVM4();
        XBAR(); RD_A(a2, 1, 1); WAITLG(8); MFMA_Q(0, 1, a1, b23); XBAR();
        // P7: Q11(o) <- a2,b23.   issue b01A(buf0, e2)
        STAGE(1, 1, 0, t3);
        XBAR(); RD_BP(b01A, 0, 0); WAITLG(4); MFMA_Q(1, 1, a2, b23); XBAR();
        // P8: Q10(o) <- a2,b01B.  issue a1(buf0, e2); WVM drains buf0.A(e2); no wait
        STAGE(1, 1, 1, t3); WVM4();
        XBAR(); RD_A(a1, 0, 0); MFMA_Q(1, 0, a2, b01B); XBAR();
    }
    asm volatile("s_waitcnt vmcnt(0) lgkmcnt(0)" ::: "memory");  // drain before epilogue

    // epilogue: D row = (lane>>4)*4 + reg, col = lane&15  [m89/m91-verified]
    const int rbase = bm + wr + lkq * 4;
    const int cbase = bn + wc + lrow;
    if (BIAS_RELU) {
        #pragma unroll
        for (int ni = 0; ni < 4; ++ni) {
            const float bv = epi[cbase + ni * 16];
            #pragma unroll
            for (int mi = 0; mi < 8; ++mi)
                #pragma unroll
                for (int r = 0; r < 4; ++r) {
                    float v = acc[mi][ni][r] + bv;
                    v = fmaxf(v, 0.f);
                    C[(size_t)(rbase + mi * 16 + r) * N + cbase + ni * 16] = f2bf(v);
                }
        }
    } else {
        #pragma unroll
        for (int mi = 0; mi < 8; ++mi)
            #pragma unroll
            for (int r = 0; r < 4; ++r) {
                const float sv = epi[rbase + mi * 16 + r];
                #pragma unroll
                for (int ni = 0; ni < 4; ++ni)
                    C[(size_t)(rbase + mi * 16 + r) * N + cbase + ni * 16] =
                        f2bf(acc[mi][ni][r] * sv);
            }
    }
}

// ---------------- classifier GEMM (N=16) ----------------
__device__ __forceinline__ float bfdot2(u32 a, u32 b, float acc) {
    float al = __uint_as_float(a << 16), ah = __uint_as_float(a & 0xffff0000u);
    float bl = __uint_as_float(b << 16), bh = __uint_as_float(b & 0xffff0000u);
    return fmaf(ah, bh, fmaf(al, bl, acc));
}

__global__ __launch_bounds__(256) void gemm_cls(
    const u16* __restrict__ hc, const u16* __restrict__ Wc2,
    const float* __restrict__ bc2, float* __restrict__ out)
{
    const int c = threadIdx.x & 15;
    const int r = threadIdx.x >> 4;              // 16 rows per block
    const int row = blockIdx.x * 16 + r;
    const uint4* hp = (const uint4*)(hc + (size_t)row * NP);
    const uint4* wp = (const uint4*)(Wc2 + (size_t)c * NP);
    float acc = 0.f;
    #pragma unroll 4
    for (int i = 0; i < NP / 8; ++i) {
        uint4 a = hp[i], b = wp[i];
        acc = bfdot2(a.x, b.x, acc);
        acc = bfdot2(a.y, b.y, acc);
        acc = bfdot2(a.z, b.z, acc);
        acc = bfdot2(a.w, b.w, acc);
    }
    out[(size_t)row * 16 + c] = acc + bc2[c];
}

// ---------------- launch ----------------

extern "C" void kernel_launch(void* const* d_in, const int* in_sizes, int n_in,
                              void* d_out, int out_size, void* d_ws, size_t ws_size,
                              hipStream_t stream) {
    const float* gene  = (const float*)d_in[0];
    const float* train = (const float*)d_in[1];
    const int*   esrc  = (const int*)d_in[2];
    const int*   edst  = (const int*)d_in[3];
    const float* W1s   = (const float*)d_in[4];
    const float* W1n   = (const float*)d_in[5];
    const float* b1    = (const float*)d_in[6];
    const float* W2s   = (const float*)d_in[7];
    const float* W2n   = (const float*)d_in[8];
    const float* b2    = (const float*)d_in[9];
    const float* Wc1   = (const float*)d_in[10];
    const float* bc1   = (const float*)d_in[11];
    const float* Wc2   = (const float*)d_in[12];
    const float* bc2   = (const float*)d_in[13];
    const int E = in_sizes[2];

    char* ws = (char*)d_ws;
    const size_t o_acnt  = 0;                       // fp32 counts [M,NP]  (later: h)
    const size_t o_acntb = 167772160;               // bf16 counts         (later: h2)
    const size_t o_mean  = 251658240;               // bf16 mean_src       (later: hc)
    const size_t o_train = 335544320;               // bf16 train [M,K1P]
    const size_t o_w1s   = 423624704;               // [NP,K1P]
    const size_t o_w1n   = 437387264;               // [NP,NP]
    const size_t o_w2s   = 450494464;
    const size_t o_w2n   = 463601664;
    const size_t o_wc1   = 476708864;
    const size_t o_gft   = 489816064;               // gene_feat^T bf16 [NP,NP]
    const size_t o_wc2   = 502923264;               // [16,NP]
    const size_t o_b1    = 503005184;
    const size_t o_b2    = 503015424;
    const size_t o_bc1   = 503025664;
    const size_t o_rdeg  = 503035904;

    float* ACNT = (float*)(ws + o_acnt);
    u16* ACNTB  = (u16*)(ws + o_acntb);
    u16* MEAN   = (u16*)(ws + o_mean);
    u16* TRAINB = (u16*)(ws + o_train);
    u16* W1S    = (u16*)(ws + o_w1s);
    u16* W1N    = (u16*)(ws + o_w1n);
    u16* W2S    = (u16*)(ws + o_w2s);
    u16* W2N    = (u16*)(ws + o_w2n);
    u16* WC1    = (u16*)(ws + o_wc1);
    u16* GFT    = (u16*)(ws + o_gft);
    u16* WC2    = (u16*)(ws + o_wc2);
    float* B1   = (float*)(ws + o_b1);
    float* B2   = (float*)(ws + o_b2);
    float* BC1  = (float*)(ws + o_bc1);
    float* RDEG = (float*)(ws + o_rdeg);
    u16* H  = (u16*)(ws + o_acnt);    // alias: counts fp32 dead after cvt+rdeg
    u16* H2 = (u16*)(ws + o_acntb);   // alias: counts bf16 dead after G1
    u16* HC = (u16*)(ws + o_mean);    // alias: mean dead after G3

    // 1. build dense counts + degree
    hipMemsetAsync(ACNT, 0, (size_t)MROWS * NP * 4, stream);
    build_counts<<<(E + 255) / 256, 256, 0, stream>>>(esrc, edst, E, ACNT);
    row_rdeg<<<MROWS, 64, 0, stream>>>(ACNT, RDEG);

    // 2. conversions / padding
    cvt_pad<<<MROWS, 256, 0, stream>>>(ACNT, ACNTB, MROWS, NP, NP);   // counts exact in bf16
    cvt_pad<<<MROWS, 256, 0, stream>>>(train, TRAINB, MROWS, 2675, K1P);
    cvt_pad<<<NP, 256, 0, stream>>>(W1s, W1S, 2500, 2675, K1P);
    cvt_pad<<<NP, 256, 0, stream>>>(W1n, W1N, 2500, 2500, NP);
    cvt_pad<<<NP, 256, 0, stream>>>(W2s, W2S, 2500, 2500, NP);
    cvt_pad<<<NP, 256, 0, stream>>>(W2n, W2N, 2500, 2500, NP);
    cvt_pad<<<NP, 256, 0, stream>>>(Wc1, WC1, 2500, 2500, NP);
    cvt_pad<<<16, 256, 0, stream>>>(Wc2, WC2, 16, 2500, NP);
    transpose_cvt<<<dim3(NP / 64, NP / 64), dim3(64, 4), 0, stream>>>(gene, GFT);
    pad_vec<<<(NP + 255) / 256, 256, 0, stream>>>(b1, B1, 2500, NP);
    pad_vec<<<(NP + 255) / 256, 256, 0, stream>>>(b2, B2, 2500, NP);
    pad_vec<<<(NP + 255) / 256, 256, 0, stream>>>(bc1, BC1, 2500, NP);

    const int NWG = (NP / 256) * (MROWS / 256);   // 640
    // 3. G1: mean_src = (A @ gene_feat) * rdeg   [bf16 out]
    gemm256<false, false><<<NWG, 512, 0, stream>>>(
        ACNTB, GFT, NP, nullptr, nullptr, 0, RDEG, MEAN, NP);
    // 4. G2: h = relu(train @ W1s^T + mean @ W1n^T + b1)
    gemm256<true, true><<<NWG, 512, 0, stream>>>(
        TRAINB, W1S, K1P, MEAN, W1N, NP, B1, H, NP);
    // 5. G3: h2 = relu(h @ W2s^T + mean @ W2n^T + b2)
    gemm256<true, true><<<NWG, 512, 0, stream>>>(
        H, W2S, NP, MEAN, W2N, NP, B2, H2, NP);
    // 6. G4: hc = relu(h2 @ Wc1^T + bc1)
    gemm256<false, true><<<NWG, 512, 0, stream>>>(
        H2, WC1, NP, nullptr, nullptr, 0, BC1, HC, NP);
    // 7. G5: out = hc @ Wc2^T + bc2
    gemm_cls<<<MROWS / 16, 256, 0, stream>>>(HC, WC2, bc2, (float*)d_out);
}

// Round 4
// 2068.631 us; speedup vs baseline: 1.0513x; 1.0513x over previous
//
#include <hip/hip_runtime.h>
#include <stdint.h>

typedef unsigned short u16;
typedef unsigned int u32;
typedef __attribute__((ext_vector_type(4))) float f32x4;
typedef __attribute__((ext_vector_type(8))) short bf16x8;

#define MROWS 16384
#define NP    2560   // padded N / K for 2500-dims
#define K1P   2688   // padded K for 2675 (train_feat / W1_self)

// ---------------- helpers ----------------

__device__ __forceinline__ u16 f2bf(float f) {
    u32 u = __float_as_uint(f);
    u32 r = (u + 0x7fffu + ((u >> 16) & 1u)) >> 16;   // round-to-nearest-even
    return (u16)r;
}

__device__ __forceinline__ void async_ld16(const void* g, void* l) {
    __builtin_amdgcn_global_load_lds((const __attribute__((address_space(1))) u32*)g,
                                     (__attribute__((address_space(3))) u32*)l,
                                     16, 0, 0);
}

__device__ __forceinline__ u32 lds_b(const void* p) {
    return (u32)(uintptr_t)(const __attribute__((address_space(3))) void*)p;
}

// ---------------- prep kernels ----------------

__global__ void cvt_pad(const float* __restrict__ src, u16* __restrict__ dst,
                        int R, int C, int Cp) {
    const int r = blockIdx.x;
    u16* drow = dst + (size_t)r * Cp;
    if (r < R) {
        const float* srow = src + (size_t)r * C;
        for (int c = threadIdx.x; c < Cp; c += blockDim.x)
            drow[c] = (c < C) ? f2bf(srow[c]) : (u16)0;
    } else {
        for (int c = threadIdx.x; c < Cp; c += blockDim.x) drow[c] = 0;
    }
}

__global__ void pad_vec(const float* __restrict__ src, float* __restrict__ dst,
                        int n, int np) {
    int i = blockIdx.x * blockDim.x + threadIdx.x;
    if (i < np) dst[i] = (i < n) ? src[i] : 0.f;
}

// gene_feat [2500,2500] fp32 -> dst [NP,NP] bf16, dst[n][k] = src[k][n], padded 0
__global__ void transpose_cvt(const float* __restrict__ src, u16* __restrict__ dst) {
    __shared__ float t[64][65];
    const int n0 = blockIdx.x * 64;
    const int k0 = blockIdx.y * 64;
    const int tx = threadIdx.x, ty = threadIdx.y;  // (64,4)
    for (int i = ty; i < 64; i += 4) {
        int k = k0 + i, n = n0 + tx;
        t[i][tx] = (k < 2500 && n < 2500) ? src[(size_t)k * 2500 + n] : 0.f;
    }
    __syncthreads();
    for (int i = ty; i < 64; i += 4)
        dst[(size_t)(n0 + i) * NP + k0 + tx] = f2bf(t[tx][i]);
}

// counts packed u8: cell (dst,src) -> byte addr dst*NP+src; atomic add into u32 word.
// Counts are Poisson(lambda ~ 0.1), max ~7 << 255: no byte overflow, bf16-exact.
__global__ void build_counts8(const int* __restrict__ esrc, const int* __restrict__ edst,
                              int E, u32* __restrict__ cnt) {
    int i = blockIdx.x * blockDim.x + threadIdx.x;
    if (i < E) {
        u32 addr = (u32)edst[i] * NP + (u32)esrc[i];
        atomicAdd(&cnt[addr >> 2], 1u << ((addr & 3u) * 8u));
    }
}

// fused: per row, read u8 counts -> rowsum -> rdeg, and write bf16 counts row.
// grid = MROWS/4 blocks x 256 threads; one wave per row.
__global__ void cnt_row(const u32* __restrict__ cnt, u16* __restrict__ acntb,
                        float* __restrict__ rdeg) {
    const int row  = blockIdx.x * 4 + (threadIdx.x >> 6);
    const int lane = threadIdx.x & 63;
    const uint4* src = (const uint4*)((const char*)cnt + (size_t)row * NP);
    u16* drow = acntb + (size_t)row * NP;
    u32 s = 0;
    for (int i = lane; i < NP / 16; i += 64) {   // 160 x uint4 per row
        uint4 v = src[i];
        u32 w[4] = {v.x, v.y, v.z, v.w};
        __align__(16) u16 o[16];
        #pragma unroll
        for (int j = 0; j < 4; ++j) {
            #pragma unroll
            for (int b = 0; b < 4; ++b) {
                u32 byte = (w[j] >> (8 * b)) & 0xffu;
                s += byte;
                o[j * 4 + b] = f2bf((float)byte);
            }
        }
        uint4* dst = (uint4*)(drow + i * 16);
        dst[0] = *(const uint4*)&o[0];
        dst[1] = *(const uint4*)&o[8];
    }
    float fs = (float)s;
    #pragma unroll
    for (int off = 32; off > 0; off >>= 1) fs += __shfl_down(fs, off, 64);
    if (lane == 0) rdeg[row] = 1.f / fmaxf(fs, 1.f);
}

// ---------------- main MFMA GEMM: 256x256, 8-phase, full one-phase-ahead reads --------
// (frozen from r3 -- verified; per-resident-block MFMA-busy ~60%, matching the m201
//  reference template. Remaining global gap is the 640-tile / 256-CU grid tail.)
// C[M,N](bf16) = epilogue( A1[M,K1] @ B1[N,K1]^T (+ A2[M,K2] @ B2[N,K2]^T) )
// 512 threads = 8 waves (2M x 4N), per-wave 128x64, BK=64.
// LDS: 2 buffers x (A 256x64 + B 256x64) bf16 = 128 KiB, chunk-XOR swizzled.

#define DSR(dst, ad, off) \
    asm volatile("ds_read_b128 %0, %1 offset:%2" : "=v"(dst) : "v"(ad), "i"(off))

#define RD_A(SET, BUF, QM) do { \
    DSR(SET[0][0], adA0, (BUF)*32768 + (QM)*8192 + 0);    \
    DSR(SET[0][1], adA1, (BUF)*32768 + (QM)*8192 + 0);    \
    DSR(SET[1][0], adA0, (BUF)*32768 + (QM)*8192 + 2048); \
    DSR(SET[1][1], adA1, (BUF)*32768 + (QM)*8192 + 2048); \
    DSR(SET[2][0], adA0, (BUF)*32768 + (QM)*8192 + 4096); \
    DSR(SET[2][1], adA1, (BUF)*32768 + (QM)*8192 + 4096); \
    DSR(SET[3][0], adA0, (BUF)*32768 + (QM)*8192 + 6144); \
    DSR(SET[3][1], adA1, (BUF)*32768 + (QM)*8192 + 6144); \
} while (0)

// B frag pair: BASE=0 -> ni{0,1} (b01), BASE=4096 -> ni{2,3} (b23)
#define RD_BP(SET, BUF, BASE) do { \
    DSR(SET[0][0], adB0, (BUF)*32768 + (BASE));        \
    DSR(SET[0][1], adB1, (BUF)*32768 + (BASE));        \
    DSR(SET[1][0], adB0, (BUF)*32768 + (BASE) + 2048); \
    DSR(SET[1][1], adB1, (BUF)*32768 + (BASE) + 2048); \
} while (0)

// counted lgkm wait + scheduler fence (rule #18: MFMA must not hoist above the wait)
#define WAITLG(N) do { \
    asm volatile("s_waitcnt lgkmcnt(" #N ")" ::: "memory"); \
    __builtin_amdgcn_sched_barrier(0); \
} while (0)

#define MFMA_Q(QM, QN, ASET, BSET) do { \
    __builtin_amdgcn_s_setprio(1); \
    _Pragma("unroll") \
    for (int mi_ = 0; mi_ < 4; ++mi_) { \
        _Pragma("unroll") \
        for (int ni_ = 0; ni_ < 2; ++ni_) { \
            f32x4 c_ = acc[(QM)*4 + mi_][(QN)*2 + ni_]; \
            c_ = __builtin_amdgcn_mfma_f32_16x16x32_bf16(ASET[mi_][0], BSET[ni_][0], c_, 0, 0, 0); \
            c_ = __builtin_amdgcn_mfma_f32_16x16x32_bf16(ASET[mi_][1], BSET[ni_][1], c_, 0, 0, 0); \
            acc[(QM)*4 + mi_][(QN)*2 + ni_] = c_; \
        } \
    } \
    __builtin_amdgcn_s_setprio(0); \
} while (0)

#define XFEN() asm volatile("" ::: "memory")
#define XBAR() do { XFEN(); __builtin_amdgcn_s_barrier(); XFEN(); } while (0)
#define WVM4() asm volatile("s_waitcnt vmcnt(4)" ::: "memory")

template<bool PAIR2, bool BIAS_RELU>
__global__ __launch_bounds__(512, 2) void gemm256(
    const u16* __restrict__ A1, const u16* __restrict__ B1, int K1,
    const u16* __restrict__ A2, const u16* __restrict__ B2, int K2,
    const float* __restrict__ epi, u16* __restrict__ C, int N)
{
    __shared__ __align__(16) u16 lA[2 * 256 * 64];
    __shared__ __align__(16) u16 lB[2 * 256 * 64];

    const int tid  = threadIdx.x;
    // bijective XCD swizzle (gridDim.x = 640, 640 % 8 == 0)
    const int nwg  = gridDim.x;
    const int orig = blockIdx.x;
    const int swz  = (orig & 7) * (nwg >> 3) + (orig >> 3);
    const int nt   = N >> 8;                 // 10 col-tiles
    const int bm   = (swz / nt) << 8;
    const int bn   = (swz % nt) << 8;

    const int wave = tid >> 6, lane = tid & 63;
    const int wr   = (wave >> 2) << 7;       // 0 or 128
    const int wc   = (wave & 3) << 6;        // 0,64,128,192
    const int lrow = lane & 15, lkq = (lane >> 4) & 3;
    const int o0   = ((lkq ^ (lrow & 7)) << 3);   // elem offset, ks=0 chunk

    // ds_read base addresses (bytes); ks=1 chunk = ks=0 chunk ^ 32 elems = ^64 B
    const u32 adA0 = lds_b(lA + (wr + lrow) * 64 + o0);
    const u32 adA1 = adA0 ^ 64;
    const u32 adB0 = lds_b(lB + (wc + lrow) * 64 + o0);
    const u32 adB1 = adB0 ^ 64;

    // staging constants: thread t -> row t>>3, physical chunk t&7 (lane-linear LDS dest)
    const int sr   = tid >> 3;
    const int pc   = tid & 7;
    const int swzc = ((pc ^ (sr & 7)) << 3); // source logical chunk offset (elems)
    u16* const dA  = lA + sr * 64 + pc * 8;
    u16* const dB  = lB + sr * 64 + pc * 8;

    const int nk1 = K1 >> 6;
    const int nkt = nk1 + (PAIR2 ? (K2 >> 6) : 0);

    f32x4 acc[8][4] = {};
    bf16x8 a1[4][2], a2[4][2], b23[2][2], b01A[2][2], b01B[2][2];

    // stage one 128-row half-tile (2 x global_load_lds / thread) of A(mat=0)/B(mat=1)
    auto STAGE = [&](int mat, int buf, int half, int kt) {
        int v = (kt < nkt) ? kt : kt - nkt;  // tail: clamp to valid tile (lands in dead region)
        const u16* base; int K, ko;
        if (!PAIR2 || v < nk1) { base = mat ? B1 : A1; K = K1; ko = v << 6; }
        else                   { base = mat ? B2 : A2; K = K2; ko = (v - nk1) << 6; }
        const int rb = (mat ? bn : bm) + (half << 7) + sr;
        u16* d = (mat ? dB : dA) + buf * 16384 + half * 8192;
        const u16* g = base + (size_t)rb * K + ko + swzc;
        async_ld16(g, d);
        async_ld16(g + (size_t)64 * K, d + 4096);
    };

    // prologue: buf0 full (tile0) + buf1.B (tile1); drain buf0, leave buf1.B in flight
    STAGE(1, 0, 0, 0); STAGE(1, 0, 1, 0);    // buf0.B
    STAGE(0, 0, 0, 0); STAGE(0, 0, 1, 0);    // buf0.A
    STAGE(1, 1, 0, 1); STAGE(1, 1, 1, 1);    // buf1.B
    WVM4();                                   // 12 -> 4: buf0 landed, buf1.B in flight
    XBAR();
    RD_BP(b01A, 0, 0);                        // issues for P1 (12 ds in flight: b01A+a1)
    RD_A(a1, 0, 0);

    const int niter = nkt >> 1;               // nkt always even here
    #pragma unroll 1
    for (int i = 0; i < niter; ++i) {
        const int t1 = 2 * i + 1, t2 = 2 * i + 2, t3 = 2 * i + 3;
        // P1: Q00(e) <- a1,b01A.  issue b23(buf0)
        STAGE(0, 1, 0, t1);
        XBAR(); RD_BP(b23, 0, 4096); WAITLG(4); MFMA_Q(0, 0, a1, b01A); XBAR();
        // P2: Q01(e) <- a1,b23.   issue a2(buf0); WVM drains buf1.B for P3
        STAGE(0, 1, 1, t1); WVM4();
        XBAR(); RD_A(a2, 0, 1); WAITLG(8); MFMA_Q(0, 1, a1, b23); XBAR();
        // P3: Q11(e) <- a2,b23.   issue b01B(buf1)
        STAGE(1, 0, 0, t2);
        XBAR(); RD_BP(b01B, 1, 0); WAITLG(4); MFMA_Q(1, 1, a2, b23); XBAR();
        // P4: Q10(e) <- a2,b01A.  issue a1(buf1); WVM drains buf1.A; no lgkm wait
        STAGE(1, 0, 1, t2); WVM4();
        XBAR(); RD_A(a1, 1, 0); MFMA_Q(1, 0, a2, b01A); XBAR();
        // P5: Q00(o) <- a1,b01B.  issue b23(buf1)
        STAGE(0, 0, 0, t2);
        XBAR(); RD_BP(b23, 1, 4096); WAITLG(4); MFMA_Q(0, 0, a1, b01B); XBAR();
        // P6: Q01(o) <- a1,b23.   issue a2(buf1); WVM drains buf0.B(e2) for P7
        STAGE(0, 0, 1, t2); WVM4();
        XBAR(); RD_A(a2, 1, 1); WAITLG(8); MFMA_Q(0, 1, a1, b23); XBAR();
        // P7: Q11(o) <- a2,b23.   issue b01A(buf0, e2)
        STAGE(1, 1, 0, t3);
        XBAR(); RD_BP(b01A, 0, 0); WAITLG(4); MFMA_Q(1, 1, a2, b23); XBAR();
        // P8: Q10(o) <- a2,b01B.  issue a1(buf0, e2); WVM drains buf0.A(e2); no wait
        STAGE(1, 1, 1, t3); WVM4();
        XBAR(); RD_A(a1, 0, 0); MFMA_Q(1, 0, a2, b01B); XBAR();
    }
    asm volatile("s_waitcnt vmcnt(0) lgkmcnt(0)" ::: "memory");  // drain before epilogue

    // epilogue: D row = (lane>>4)*4 + reg, col = lane&15  [m89/m91-verified]
    const int rbase = bm + wr + lkq * 4;
    const int cbase = bn + wc + lrow;
    if (BIAS_RELU) {
        #pragma unroll
        for (int ni = 0; ni < 4; ++ni) {
            const float bv = epi[cbase + ni * 16];
            #pragma unroll
            for (int mi = 0; mi < 8; ++mi)
                #pragma unroll
                for (int r = 0; r < 4; ++r) {
                    float v = acc[mi][ni][r] + bv;
                    v = fmaxf(v, 0.f);
                    C[(size_t)(rbase + mi * 16 + r) * N + cbase + ni * 16] = f2bf(v);
                }
        }
    } else {
        #pragma unroll
        for (int mi = 0; mi < 8; ++mi)
            #pragma unroll
            for (int r = 0; r < 4; ++r) {
                const float sv = epi[rbase + mi * 16 + r];
                #pragma unroll
                for (int ni = 0; ni < 4; ++ni)
                    C[(size_t)(rbase + mi * 16 + r) * N + cbase + ni * 16] =
                        f2bf(acc[mi][ni][r] * sv);
            }
    }
}

// ---------------- classifier GEMM (N=16) ----------------
__device__ __forceinline__ float bfdot2(u32 a, u32 b, float acc) {
    float al = __uint_as_float(a << 16), ah = __uint_as_float(a & 0xffff0000u);
    float bl = __uint_as_float(b << 16), bh = __uint_as_float(b & 0xffff0000u);
    return fmaf(ah, bh, fmaf(al, bl, acc));
}

__global__ __launch_bounds__(256) void gemm_cls(
    const u16* __restrict__ hc, const u16* __restrict__ Wc2,
    const float* __restrict__ bc2, float* __restrict__ out)
{
    const int c = threadIdx.x & 15;
    const int r = threadIdx.x >> 4;              // 16 rows per block
    const int row = blockIdx.x * 16 + r;
    const uint4* hp = (const uint4*)(hc + (size_t)row * NP);
    const uint4* wp = (const uint4*)(Wc2 + (size_t)c * NP);
    float acc = 0.f;
    #pragma unroll 4
    for (int i = 0; i < NP / 8; ++i) {
        uint4 a = hp[i], b = wp[i];
        acc = bfdot2(a.x, b.x, acc);
        acc = bfdot2(a.y, b.y, acc);
        acc = bfdot2(a.z, b.z, acc);
        acc = bfdot2(a.w, b.w, acc);
    }
    out[(size_t)row * 16 + c] = acc + bc2[c];
}

// ---------------- launch ----------------

extern "C" void kernel_launch(void* const* d_in, const int* in_sizes, int n_in,
                              void* d_out, int out_size, void* d_ws, size_t ws_size,
                              hipStream_t stream) {
    const float* gene  = (const float*)d_in[0];
    const float* train = (const float*)d_in[1];
    const int*   esrc  = (const int*)d_in[2];
    const int*   edst  = (const int*)d_in[3];
    const float* W1s   = (const float*)d_in[4];
    const float* W1n   = (const float*)d_in[5];
    const float* b1    = (const float*)d_in[6];
    const float* W2s   = (const float*)d_in[7];
    const float* W2n   = (const float*)d_in[8];
    const float* b2    = (const float*)d_in[9];
    const float* Wc1   = (const float*)d_in[10];
    const float* bc1   = (const float*)d_in[11];
    const float* Wc2   = (const float*)d_in[12];
    const float* bc2   = (const float*)d_in[13];
    const int E = in_sizes[2];

    char* ws = (char*)d_ws;
    const size_t o_acnt  = 0;                       // u8 counts [M,NP] 40MB (later: h)
    const size_t o_acntb = 167772160;               // bf16 counts         (later: h2)
    const size_t o_mean  = 251658240;               // bf16 mean_src       (later: hc)
    const size_t o_train = 335544320;               // bf16 train [M,K1P]
    const size_t o_w1s   = 423624704;               // [NP,K1P]
    const size_t o_w1n   = 437387264;               // [NP,NP]
    const size_t o_w2s   = 450494464;
    const size_t o_w2n   = 463601664;
    const size_t o_wc1   = 476708864;
    const size_t o_gft   = 489816064;               // gene_feat^T bf16 [NP,NP]
    const size_t o_wc2   = 502923264;               // [16,NP]
    const size_t o_b1    = 503005184;
    const size_t o_b2    = 503015424;
    const size_t o_bc1   = 503025664;
    const size_t o_rdeg  = 503035904;

    u32* CNT8   = (u32*)(ws + o_acnt);
    u16* ACNTB  = (u16*)(ws + o_acntb);
    u16* MEAN   = (u16*)(ws + o_mean);
    u16* TRAINB = (u16*)(ws + o_train);
    u16* W1S    = (u16*)(ws + o_w1s);
    u16* W1N    = (u16*)(ws + o_w1n);
    u16* W2S    = (u16*)(ws + o_w2s);
    u16* W2N    = (u16*)(ws + o_w2n);
    u16* WC1    = (u16*)(ws + o_wc1);
    u16* GFT    = (u16*)(ws + o_gft);
    u16* WC2    = (u16*)(ws + o_wc2);
    float* B1   = (float*)(ws + o_b1);
    float* B2   = (float*)(ws + o_b2);
    float* BC1  = (float*)(ws + o_bc1);
    float* RDEG = (float*)(ws + o_rdeg);
    u16* H  = (u16*)(ws + o_acnt);    // alias: u8 counts dead after cnt_row
    u16* H2 = (u16*)(ws + o_acntb);   // alias: bf16 counts dead after G1
    u16* HC = (u16*)(ws + o_mean);    // alias: mean dead after G3

    // 1. build packed-u8 counts + fused (rowsum -> rdeg, u8 -> bf16) pass
    hipMemsetAsync(CNT8, 0, (size_t)MROWS * NP, stream);
    build_counts8<<<(E + 255) / 256, 256, 0, stream>>>(esrc, edst, E, CNT8);
    cnt_row<<<MROWS / 4, 256, 0, stream>>>(CNT8, ACNTB, RDEG);

    // 2. conversions / padding
    cvt_pad<<<MROWS, 256, 0, stream>>>(train, TRAINB, MROWS, 2675, K1P);
    cvt_pad<<<NP, 256, 0, stream>>>(W1s, W1S, 2500, 2675, K1P);
    cvt_pad<<<NP, 256, 0, stream>>>(W1n, W1N, 2500, 2500, NP);
    cvt_pad<<<NP, 256, 0, stream>>>(W2s, W2S, 2500, 2500, NP);
    cvt_pad<<<NP, 256, 0, stream>>>(W2n, W2N, 2500, 2500, NP);
    cvt_pad<<<NP, 256, 0, stream>>>(Wc1, WC1, 2500, 2500, NP);
    cvt_pad<<<16, 256, 0, stream>>>(Wc2, WC2, 16, 2500, NP);
    transpose_cvt<<<dim3(NP / 64, NP / 64), dim3(64, 4), 0, stream>>>(gene, GFT);
    pad_vec<<<(NP + 255) / 256, 256, 0, stream>>>(b1, B1, 2500, NP);
    pad_vec<<<(NP + 255) / 256, 256, 0, stream>>>(b2, B2, 2500, NP);
    pad_vec<<<(NP + 255) / 256, 256, 0, stream>>>(bc1, BC1, 2500, NP);

    const int NWG = (NP / 256) * (MROWS / 256);   // 640
    // 3. G1: mean_src = (A @ gene_feat) * rdeg   [bf16 out]
    gemm256<false, false><<<NWG, 512, 0, stream>>>(
        ACNTB, GFT, NP, nullptr, nullptr, 0, RDEG, MEAN, NP);
    // 4. G2: h = relu(train @ W1s^T + mean @ W1n^T + b1)
    gemm256<true, true><<<NWG, 512, 0, stream>>>(
        TRAINB, W1S, K1P, MEAN, W1N, NP, B1, H, NP);
    // 5. G3: h2 = relu(h @ W2s^T + mean @ W2n^T + b2)
    gemm256<true, true><<<NWG, 512, 0, stream>>>(
        H, W2S, NP, MEAN, W2N, NP, B2, H2, NP);
    // 6. G4: hc = relu(h2 @ Wc1^T + bc1)
    gemm256<false, true><<<NWG, 512, 0, stream>>>(
        H2, WC1, NP, nullptr, nullptr, 0, BC1, HC, NP);
    // 7. G5: out = hc @ Wc2^T + bc2
    gemm_cls<<<MROWS / 16, 256, 0, stream>>>(HC, WC2, bc2, (float*)d_out);
}